// Round 3
// baseline (147.324 us; speedup 1.0000x reference)
//
#include <hip/hip_runtime.h>
#include <hip/hip_bf16.h>

#define IMG_SIZE 256
#define NPIX (IMG_SIZE * IMG_SIZE)
#define KSEL 5
#define BS 8
#define LL 64
#define LUSED 63          // row l=63's top-k is discarded by the roll
#define NTHREADS 256
#define RROWS 7           // rows (same image) per block; 63 = 9*7 exact
#define NGRP 9            // row-groups per image
#define SPLIT 8           // image chunks
#define CHUNK_PX (NPIX / SPLIT)        // 8192 pixels
#define CHUNK_V4 (CHUNK_PX / 4)        // 2048 float4
#define ITERS (CHUNK_V4 / NTHREADS)    // 8

typedef unsigned long long ull;

// Branchless sorted-insert: loc[] ascending; bubble key in, evict the max.
__device__ __forceinline__ void sort_insert(ull loc[KSEL], ull key) {
    #pragma unroll
    for (int j = 0; j < KSEL; ++j) {
        const ull a = loc[j];
        const bool lt = key < a;
        loc[j] = lt ? key : a;
        key    = lt ? a : key;
    }
}

// Merge two ascending 5-lists, keep smallest 5 into a.
__device__ __forceinline__ void merge5(ull* a, const ull* b) {
    ull out[KSEL];
    int ia = 0, ib = 0;
    #pragma unroll
    for (int j = 0; j < KSEL; ++j) {
        const ull va = a[ia], vb = b[ib];
        const bool ta = va <= vb;
        out[j] = ta ? va : vb;
        ia += ta ? 1 : 0;
        ib += ta ? 0 : 1;
    }
    #pragma unroll
    for (int j = 0; j < KSEL; ++j) a[j] = out[j];
}

__device__ __forceinline__ ull
pix_key(float r0, float r1, float r2, float c0, float c1, float c2, int pix) {
    // Match numpy f32 exactly: no FMA contraction, ((d0^2+d1^2)+d2^2).
    float d0 = __fsub_rn(r0, c0);
    float d1 = __fsub_rn(r1, c1);
    float d2 = __fsub_rn(r2, c2);
    float s = __fadd_rn(__fadd_rn(__fmul_rn(d0, d0), __fmul_rn(d1, d1)), __fmul_rn(d2, d2));
    // s >= 0 -> uint bit order == float order; low bits = pixel idx -> jax
    // top_k lower-index-first tie-break.
    return ((ull)__float_as_uint(s) << 32) | (unsigned int)pix;
}

// One block per (image b, row-group g, chunk): scan chunk once, feed RROWS
// ladders. Emit sorted top-5 per (row, chunk).
__global__ __launch_bounds__(NTHREADS)
void topk_kernel(const float* __restrict__ preds,
                 const float* __restrict__ imgs,
                 ull* __restrict__ keys_out) {
    const int bx = blockIdx.x;
    const int chunk = bx & (SPLIT - 1);
    const int grp = bx >> 3;            // 0..71
    const int b = grp / NGRP;
    const int g = grp % NGRP;
    const int t = threadIdx.x;

    const float* imgb = imgs + (size_t)b * 3 * NPIX;

    // Per-row pooled centers (wave-uniform scalar-ish loads).
    float c0[RROWS], c1[RROWS], c2[RROWS];
    #pragma unroll
    for (int r = 0; r < RROWS; ++r) {
        const int l = g * RROWS + r;
        // Scrambled pooled indexing: flat i = l*bs + b; pos from preds[i//64, i%64].
        const int i = l * BS + b;
        const int pb = i >> 6;
        const int pl = i & 63;
        const float px = preds[pb * (LL * 8) + pl * 8 + 0];
        const float py = preds[pb * (LL * 8) + pl * 8 + 1];
        const float cx = __fsub_rn(__fmul_rn(px, 256.0f), 0.5f);
        const float cy = __fsub_rn(__fmul_rn(py, 256.0f), 0.5f);
        const int ix = (int)rintf(cx);   // round half to even == jnp.rint
        const int iy = (int)rintf(cy);
        const bool valid = (ix >= 0) && (ix < IMG_SIZE) && (iy >= 0) && (iy < IMG_SIZE);
        const int ixc = min(max(ix, 0), IMG_SIZE - 1);
        const int iyc = min(max(iy, 0), IMG_SIZE - 1);
        const float vmul = valid ? 1.0f : 0.0f;
        c0[r] = imgb[0 * NPIX + iyc * IMG_SIZE + ixc] * vmul;
        c1[r] = imgb[1 * NPIX + iyc * IMG_SIZE + ixc] * vmul;
        c2[r] = imgb[2 * NPIX + iyc * IMG_SIZE + ixc] * vmul;
    }

    const float4* p0 = (const float4*)(imgb + 0 * NPIX);
    const float4* p1 = (const float4*)(imgb + 1 * NPIX);
    const float4* p2 = (const float4*)(imgb + 2 * NPIX);

    ull lad[RROWS][KSEL];
    #pragma unroll
    for (int r = 0; r < RROWS; ++r)
        #pragma unroll
        for (int j = 0; j < KSEL; ++j) lad[r][j] = 0xFFFFFFFFFFFFFFFFULL;

    const int vbase = chunk * CHUNK_V4;
    #pragma unroll 1
    for (int it = 0; it < ITERS; ++it) {
        const int v = vbase + it * NTHREADS + t;
        const float4 r0 = p0[v];
        const float4 r1 = p1[v];
        const float4 r2 = p2[v];
        const int base = v * 4;
        #pragma unroll
        for (int r = 0; r < RROWS; ++r) {
            sort_insert(lad[r], pix_key(r0.x, r1.x, r2.x, c0[r], c1[r], c2[r], base + 0));
            sort_insert(lad[r], pix_key(r0.y, r1.y, r2.y, c0[r], c1[r], c2[r], base + 1));
            sort_insert(lad[r], pix_key(r0.z, r1.z, r2.z, c0[r], c1[r], c2[r], base + 2));
            sort_insert(lad[r], pix_key(r0.w, r1.w, r2.w, c0[r], c1[r], c2[r], base + 3));
        }
    }

    // Block-level merge, one row at a time (reuse one 10 KB LDS buffer).
    __shared__ ull sk[NTHREADS * KSEL];
    #pragma unroll 1
    for (int r = 0; r < RROWS; ++r) {
        __syncthreads();   // previous row's reads done before overwrite
        #pragma unroll
        for (int j = 0; j < KSEL; ++j) sk[t * KSEL + j] = lad[r][j];
        __syncthreads();
        for (int s = NTHREADS / 2; s > 0; s >>= 1) {
            if (t < s) {
                ull a[KSEL], bb[KSEL];
                #pragma unroll
                for (int j = 0; j < KSEL; ++j) { a[j] = sk[t * KSEL + j]; bb[j] = sk[(t + s) * KSEL + j]; }
                merge5(a, bb);
                #pragma unroll
                for (int j = 0; j < KSEL; ++j) sk[t * KSEL + j] = a[j];
            }
            __syncthreads();
        }
        if (t < KSEL) {
            const int rid = b * LUSED + g * RROWS + r;   // 0..503
            keys_out[((size_t)rid * SPLIT + chunk) * KSEL + t] = sk[t];
        }
    }
}

// Epilogue: one thread per loss row. Merge the SPLIT partial top-5s of row
// (b, l-1), min positional distance over the 5 pixels (== loss), block-reduce.
__global__ __launch_bounds__(512)
void finalize_kernel(const float* __restrict__ preds,
                     const ull* __restrict__ keys,
                     float* __restrict__ out) {
    const int t = threadIdx.x;           // 512 threads: (b,l) = (t>>6, t&63)
    const int b = t >> 6;
    const int l = t & 63;
    float loss = 0.0f;

    if (l >= 1) {
        const float px = preds[b * (LL * 8) + l * 8 + 0];
        const float py = preds[b * (LL * 8) + l * 8 + 1];
        const int rid = b * LUSED + (l - 1);   // tgt_down[:,l] = tgt[:,l-1]

        ull loc[KSEL];
        #pragma unroll
        for (int j = 0; j < KSEL; ++j) loc[j] = 0xFFFFFFFFFFFFFFFFULL;
        #pragma unroll 1
        for (int s = 0; s < SPLIT; ++s) {
            #pragma unroll
            for (int k = 0; k < KSEL; ++k) {
                sort_insert(loc, keys[((size_t)rid * SPLIT + s) * KSEL + k]);
            }
        }

        float best = 3.4028235e38f;
        #pragma unroll
        for (int k = 0; k < KSEL; ++k) {
            const int ixk = (int)(loc[k] & 0xFFFFFFFFULL);
            const float tx = (float)(ixk & 255) * (1.0f / 256.0f);   // exact /256
            const float ty = (float)(ixk >> 8) * (1.0f / 256.0f);
            const float dx = __fsub_rn(px, tx);
            const float dy = __fsub_rn(py, ty);
            const float dist = __fadd_rn(__fmul_rn(dx, dx), __fmul_rn(dy, dy));
            best = dist < best ? dist : best;
        }
        loss = best;
    }

    __shared__ float red[512];
    red[t] = loss;
    __syncthreads();
    for (int s = 256; s > 0; s >>= 1) {
        if (t < s) red[t] += red[t + s];
        __syncthreads();
    }
    if (t == 0) {
        out[0] = red[0] / (float)(BS * (LL - 1));
    }
}

extern "C" void kernel_launch(void* const* d_in, const int* in_sizes, int n_in,
                              void* d_out, int out_size, void* d_ws, size_t ws_size,
                              hipStream_t stream) {
    const float* preds = (const float*)d_in[0];   // (8, 64, 8) f32
    const float* imgs  = (const float*)d_in[1];   // (8, 3, 256, 256) f32
    float* out = (float*)d_out;                   // scalar f32
    ull* keys = (ull*)d_ws;                       // 504 * 8 * 5 u64 = 161 KB

    topk_kernel<<<dim3(BS * NGRP * SPLIT), dim3(NTHREADS), 0, stream>>>(preds, imgs, keys);
    finalize_kernel<<<dim3(1), dim3(512), 0, stream>>>(preds, keys, out);
}